// Round 2
// baseline (319.592 us; speedup 1.0000x reference)
//
#include <hip/hip_runtime.h>
#include <hip/hip_bf16.h>

#define HID    1024
#define NBATCH 32
#define SRC    2048
#define MROWS  (NBATCH * SRC)   // 65536
#define BM     256
#define BN     256
#define BK     64
#define NTILES (HID / BK)       // 16

typedef _Float16 f16;
typedef f16   f16x8 __attribute__((ext_vector_type(8)));
typedef f16   f16x4 __attribute__((ext_vector_type(4)));
typedef float f32x4 __attribute__((ext_vector_type(4)));

#define BAR()   asm volatile("s_barrier" ::: "memory")
#define LGKM0() asm volatile("s_waitcnt lgkmcnt(0)" ::: "memory")

__device__ __forceinline__ float fast_tanh(float x) {
  x = fminf(fmaxf(x, -15.f), 15.f);
  float e = __expf(2.f * x);
  return (e - 1.f) / (e + 1.f);
}

// swizzled LDS address: tile row-major [256][64] f16 (128 B rows),
// col ^= (row&7)<<3  -> 8 rows spread over 8 distinct 16B slots (bank-free b128)
__device__ __forceinline__ f16* LAp(char* lds, int c, int row, int col) {
  return (f16*)(lds + c * 65536 + row * 128 + ((col ^ ((row & 7) << 3)) << 1));
}
__device__ __forceinline__ f16* LBp(char* lds, int c, int row, int col) {
  return (f16*)(lds + c * 65536 + 32768 + row * 128 + ((col ^ ((row & 7) << 3)) << 1));
}

// ---------------------------------------------------------------- kernel 1
// W_e (attn_w[:, HID:]) f32 -> f16 row-major [o][h]
__global__ void convw_k(const float* __restrict__ attn_w, f16* __restrict__ Wf) {
  int idx = blockIdx.x * 256 + threadIdx.x;
  int j = idx * 4;
  int o = j >> 10, h = j & 1023;
  f32x4 d = *(const f32x4*)(attn_w + (size_t)o * 2048 + HID + h);
  f16x4 q = { (f16)d[0], (f16)d[1], (f16)d[2], (f16)d[3] };
  *(f16x4*)(Wf + (size_t)o * HID + h) = q;
}

// ---------------------------------------------------------------- kernel 2
// hvec[b][o] = sum_h hidden[b][h] * attn_w[o][h] + attn_b[o]   (exact fp32)
__global__ void hvec_k(const float* __restrict__ hidden,
                       const float* __restrict__ attn_w,
                       const float* __restrict__ attn_b,
                       float* __restrict__ hvec) {
  int idx = blockIdx.x * 256 + threadIdx.x;
  int b = idx >> 10, o = idx & 1023;
  const float* wrow = attn_w + (size_t)o * 2048;
  const float* hrow = hidden + (size_t)b * HID;
  float acc = 0.f;
  for (int h = 0; h < HID; h += 4) {
    f32x4 wv = *(const f32x4*)(wrow + h);
    f32x4 hv = *(const f32x4*)(hrow + h);
    acc += wv[0]*hv[0] + wv[1]*hv[1] + wv[2]*hv[2] + wv[3]*hv[3];
  }
  hvec[idx] = acc + attn_b[o];
}

// ---------------------------------------------------------------- kernel 3
// 256x256 tile, BK=64, 8 waves (2x4), 4 phases/K-tile, double-buffered 128 KB LDS.
// A reg-staged f32->f16 (issue ph0/ph1, cvt+write ph2/ph3), B reg-staged f16.
// Fused epilogue: part[n_idx][row] = sum_o tanh(C+hvec)*v over this block's 256 o's.

#define CVT8(lo, hi) (f16x8){ (f16)(lo)[0], (f16)(lo)[1], (f16)(lo)[2], (f16)(lo)[3], \
                              (f16)(hi)[0], (f16)(hi)[1], (f16)(hi)[2], (f16)(hi)[3] }

#define ISSUE_A1(t) { const float* p_ = Ab + (size_t)srow * HID + (t) * BK + scolh; \
  sa0 = *(const f32x4*)p_; sa1 = *(const f32x4*)(p_ + 4); \
  sa2 = *(const f32x4*)(p_ + 8); sa3 = *(const f32x4*)(p_ + 12); }
#define ISSUE_A2(t) { const float* p_ = Ab + (size_t)srow * HID + (t) * BK + scolh + 16; \
  sa4 = *(const f32x4*)p_; sa5 = *(const f32x4*)(p_ + 4); \
  sa6 = *(const f32x4*)(p_ + 8); sa7 = *(const f32x4*)(p_ + 12); }
#define ISSUE_B(t)  { const f16* p_ = Bb + (size_t)srow * HID + (t) * BK + scolh; \
  sb0 = *(const f16x8*)p_; sb1 = *(const f16x8*)(p_ + 8); \
  sb2 = *(const f16x8*)(p_ + 16); sb3 = *(const f16x8*)(p_ + 24); }
#define WRITE_A1(cc) { *(f16x8*)LAp(lds, cc, srow, scolh)      = CVT8(sa0, sa1); \
                       *(f16x8*)LAp(lds, cc, srow, scolh + 8)  = CVT8(sa2, sa3); }
#define WRITE_A2(cc) { *(f16x8*)LAp(lds, cc, srow, scolh + 16) = CVT8(sa4, sa5); \
                       *(f16x8*)LAp(lds, cc, srow, scolh + 24) = CVT8(sa6, sa7); }
#define WRITE_B(cc)  { *(f16x8*)LBp(lds, cc, srow, scolh)      = sb0; \
                       *(f16x8*)LBp(lds, cc, srow, scolh + 8)  = sb1; \
                       *(f16x8*)LBp(lds, cc, srow, scolh + 16) = sb2; \
                       *(f16x8*)LBp(lds, cc, srow, scolh + 24) = sb3; }

#define TILE_BODY(cC, tn, DOSTAGE) { \
  const int cn_ = (cC) ^ 1; \
  f16x8 bF[4][2]; \
  _Pragma("unroll") for (int n = 0; n < 4; ++n) \
  _Pragma("unroll") for (int ks = 0; ks < 2; ++ks) \
    bF[n][ks] = *(const f16x8*)LBp(lds, (cC), wc * 64 + n * 16 + lr, ks * 32 + lg * 8); \
  _Pragma("unroll") for (int p = 0; p < 4; ++p) { \
    f16x8 aF[2][2]; \
    _Pragma("unroll") for (int i = 0; i < 2; ++i) \
    _Pragma("unroll") for (int ks = 0; ks < 2; ++ks) \
      aF[i][ks] = *(const f16x8*)LAp(lds, (cC), wr * 128 + (p * 2 + i) * 16 + lr, ks * 32 + lg * 8); \
    if (DOSTAGE) { \
      if (p == 0) { ISSUE_A1(tn); } \
      if (p == 1) { ISSUE_A2(tn); ISSUE_B(tn); } \
      if (p == 2) { WRITE_A1(cn_); } \
      if (p == 3) { WRITE_A2(cn_); WRITE_B(cn_); } \
    } \
    __builtin_amdgcn_s_setprio(1); \
    _Pragma("unroll") for (int ks = 0; ks < 2; ++ks) \
    _Pragma("unroll") for (int i = 0; i < 2; ++i) \
    _Pragma("unroll") for (int n = 0; n < 4; ++n) \
      acc[p * 2 + i][n] = __builtin_amdgcn_mfma_f32_16x16x32_f16(aF[i][ks], bF[n][ks], acc[p * 2 + i][n], 0, 0, 0); \
    __builtin_amdgcn_s_setprio(0); \
    if (p == 3) { LGKM0(); } \
    BAR(); \
  } }

__global__ __launch_bounds__(512, 2) void gemm_fused(
    const float* __restrict__ A,     // (MROWS, 1024) f32
    const f16*  __restrict__ Wf,     // (1024, 1024) f16
    const float* __restrict__ hvec,  // (32, 1024)
    const float* __restrict__ v,     // (1024)
    float* __restrict__ part)        // (4, MROWS)
{
  extern __shared__ __align__(16) char lds[];   // 131072 B: 2 x (A 32K + B 32K)

  int bid = blockIdx.x;
  int wg = (bid & 7) * 128 + (bid >> 3);        // bijective XCD swizzle (1024 % 8 == 0)
  int m_idx = wg >> 2, n_idx = wg & 3;          // n fastest: 4 n-tiles share A panel in L2
  long row0 = (long)m_idx * BM;
  int o0 = n_idx * BN;
  int b = (int)(row0 >> 11);                    // 2048 rows per batch, tiles never straddle

  int tid = threadIdx.x;
  int l = tid & 63, w = tid >> 6;               // 8 waves
  int wr = w >> 2, wc = w & 3;                  // 2 (M) x 4 (N); per-wave 128x64
  int lr = l & 15, lg = l >> 4;

  // staging map: 2 threads per tile row, 32 elements each
  int srow = tid >> 1, scolh = (tid & 1) * 32;

  const float* Ab = A + row0 * HID;
  const f16*   Bb = Wf + (size_t)o0 * HID;

  f32x4 acc[8][4];
#pragma unroll
  for (int m = 0; m < 8; ++m)
#pragma unroll
    for (int n = 0; n < 4; ++n) acc[m][n] = (f32x4){0.f, 0.f, 0.f, 0.f};

  f32x4 sa0, sa1, sa2, sa3, sa4, sa5, sa6, sa7;
  f16x8 sb0, sb1, sb2, sb3;

  // ---- prologue: stage tile 0 into buf 0
  ISSUE_A1(0); ISSUE_A2(0); ISSUE_B(0);
  WRITE_A1(0); WRITE_A2(0); WRITE_B(0);
  LGKM0(); BAR();

  // ---- main loop: compute T from buf[T&1], stage T+1 into buf[(T&1)^1]
  for (int T = 0; T < NTILES - 1; ++T) {
    const int c = T & 1;
    TILE_BODY(c, T + 1, 1);
  }
  // ---- last tile, no staging
  TILE_BODY((NTILES - 1) & 1, 0, 0);

  // ---- fused epilogue: tanh(C + hvec) . v, reduced over this block's 256 o's
  float hvv[4], vvv[4];
#pragma unroll
  for (int n = 0; n < 4; ++n) {
    int o = o0 + wc * 64 + n * 16 + lr;
    hvv[n] = hvec[b * HID + o];
    vvv[n] = v[o];
  }
  float* scf = (float*)lds;   // 4 KB scratch, aliases buf0 (dead)
  __syncthreads();
#pragma unroll
  for (int m = 0; m < 8; ++m) {
#pragma unroll
    for (int r = 0; r < 4; ++r) {
      float s = 0.f;
#pragma unroll
      for (int n = 0; n < 4; ++n)
        s += fast_tanh(acc[m][n][r] + hvv[n]) * vvv[n];
      s += __shfl_xor(s, 1); s += __shfl_xor(s, 2);
      s += __shfl_xor(s, 4); s += __shfl_xor(s, 8);
      if (lr == 0) scf[wc * 256 + wr * 128 + m * 16 + lg * 4 + r] = s;
    }
  }
  __syncthreads();
  if (tid < 256) {
    float sum = scf[tid] + scf[256 + tid] + scf[512 + tid] + scf[768 + tid];
    part[(size_t)n_idx * MROWS + row0 + tid] = sum;
  }
}

// ---------------------------------------------------------------- kernel 4
// scores[b][s] = sum of 4 partials; softmax over s (2048) per batch b
__global__ void softmax_k(const float* __restrict__ part, float* __restrict__ out) {
  int b = blockIdx.x;
  __shared__ float srow[SRC];
  __shared__ float red[8];
  int tid = threadIdx.x;  // 256

  float lmax = -1e30f;
  for (int i = tid; i < SRC; i += 256) {
    float s = 0.f;
#pragma unroll
    for (int t = 0; t < 4; ++t)
      s += part[(size_t)t * MROWS + (size_t)b * SRC + i];
    srow[i] = s;
    lmax = fmaxf(lmax, s);
  }
#pragma unroll
  for (int off = 32; off >= 1; off >>= 1)
    lmax = fmaxf(lmax, __shfl_xor(lmax, off));
  if ((tid & 63) == 0) red[tid >> 6] = lmax;
  __syncthreads();
  float bmax = fmaxf(fmaxf(red[0], red[1]), fmaxf(red[2], red[3]));

  float lsum = 0.f;
  for (int i = tid; i < SRC; i += 256) {
    float e = __expf(srow[i] - bmax);
    srow[i] = e;
    lsum += e;
  }
#pragma unroll
  for (int off = 32; off >= 1; off >>= 1)
    lsum += __shfl_xor(lsum, off);
  if ((tid & 63) == 0) red[4 + (tid >> 6)] = lsum;
  __syncthreads();
  float inv = 1.f / (red[4] + red[5] + red[6] + red[7]);
  for (int i = tid; i < SRC; i += 256)
    out[(size_t)b * SRC + i] = srow[i] * inv;
}

// ---------------------------------------------------------------- launch
extern "C" void kernel_launch(void* const* d_in, const int* in_sizes, int n_in,
                              void* d_out, int out_size, void* d_ws, size_t ws_size,
                              hipStream_t stream) {
  const float* hidden = (const float*)d_in[0];
  const float* enc    = (const float*)d_in[1];
  const float* attn_w = (const float*)d_in[2];
  const float* attn_b = (const float*)d_in[3];
  const float* v      = (const float*)d_in[4];
  float* out = (float*)d_out;

  char* ws = (char*)d_ws;
  f16*   Wf   = (f16*)ws;                                 // 2 MB
  float* hv   = (float*)(ws + (2u << 20));                // 128 KB
  float* part = (float*)(ws + (2u << 20) + (512u << 10)); // 1 MB (4 x 65536 f32)

  convw_k<<<1024, 256, 0, stream>>>(attn_w, Wf);
  hvec_k <<<128,  256, 0, stream>>>(hidden, attn_w, attn_b, hv);
  gemm_fused<<<1024, 512, 131072, stream>>>(enc, Wf, hv, v, part);
  softmax_k<<<NBATCH, 256, 0, stream>>>(part, out);
}

// Round 3
// 310.726 us; speedup vs baseline: 1.0285x; 1.0285x over previous
//
#include <hip/hip_runtime.h>
#include <hip/hip_bf16.h>

#define HID    1024
#define NBATCH 32
#define SRC    2048
#define MROWS  (NBATCH * SRC)   // 65536

typedef _Float16 f16;
typedef f16   f16x8 __attribute__((ext_vector_type(8)));
typedef f16   f16x4 __attribute__((ext_vector_type(4)));
typedef float f32x4 __attribute__((ext_vector_type(4)));

#define BAR()    asm volatile("s_barrier" ::: "memory")
#define VMCNT(n) asm volatile("s_waitcnt vmcnt(" #n ")" ::: "memory")

__device__ __forceinline__ void gload_lds16(const void* g, void* l) {
  __builtin_amdgcn_global_load_lds(
      (const __attribute__((address_space(1))) void*)g,
      (__attribute__((address_space(3))) void*)l, 16, 0, 0);
}

__device__ __forceinline__ float fast_tanh(float x) {
  x = fminf(fmaxf(x, -15.f), 15.f);
  float e = __expf(2.f * x);
  return (e - 1.f) / (e + 1.f);
}

// ---------------------------------------------------------------- kernel 1
// W_e (attn_w[:, HID:]) f32 -> f16 row-major [o][h]
__global__ void convw_k(const float* __restrict__ attn_w, f16* __restrict__ Wf) {
  int idx = blockIdx.x * 256 + threadIdx.x;
  int j = idx * 4;
  int o = j >> 10, h = j & 1023;
  f32x4 d = *(const f32x4*)(attn_w + (size_t)o * 2048 + HID + h);
  f16x4 q = { (f16)d[0], (f16)d[1], (f16)d[2], (f16)d[3] };
  *(f16x4*)(Wf + (size_t)o * HID + h) = q;
}

// ---------------------------------------------------------------- kernel 2
// hvec[b][o] = sum_h hidden[b][h] * attn_w[o][h] + attn_b[o]   (exact fp32)
__global__ void hvec_k(const float* __restrict__ hidden,
                       const float* __restrict__ attn_w,
                       const float* __restrict__ attn_b,
                       float* __restrict__ hvec) {
  int idx = blockIdx.x * 256 + threadIdx.x;
  int b = idx >> 10, o = idx & 1023;
  const float* wrow = attn_w + (size_t)o * 2048;
  const float* hrow = hidden + (size_t)b * HID;
  float acc = 0.f;
  for (int h = 0; h < HID; h += 4) {
    f32x4 wv = *(const f32x4*)(wrow + h);
    f32x4 hv = *(const f32x4*)(hrow + h);
    acc += wv[0]*hv[0] + wv[1]*hv[1] + wv[2]*hv[2] + wv[3]*hv[3];
  }
  hvec[idx] = acc + attn_b[o];
}

// ---------------------------------------------------------------- kernel 2b
// A f32 -> f16 streaming convert (65536 x 1024)
__global__ void convA_k(const float* __restrict__ A, f16* __restrict__ Af) {
  size_t i = ((size_t)blockIdx.x * 256 + threadIdx.x) * 8;
  f32x4 d0 = *(const f32x4*)(A + i);
  f32x4 d1 = *(const f32x4*)(A + i + 4);
  f16x8 q = { (f16)d0[0], (f16)d0[1], (f16)d0[2], (f16)d0[3],
              (f16)d1[0], (f16)d1[1], (f16)d1[2], (f16)d1[3] };
  *(f16x8*)(Af + i) = q;
}

// ---------------------------------------------------------------- kernel 3 (fast path)
// Pure-f16 GEMM, BM=256 BN=128 BK=64, 8 waves (2M x 4N), TRIPLE-buffered LDS
// (3 x 48 KB), depth-2 prefetch via global_load_lds + counted vmcnt(6).
// Swizzle: LDS dest linear; per-lane GLOBAL source col XOR'd; ds_read XOR'd (T2, rule 21).
// One raw s_barrier per K-tile. Fused tanh(C+hvec).v epilogue -> part[8][MROWS].

#define STG(T) do { \
  char* la_ = lds + ((T) % 3) * 49152; char* lb_ = la_ + 32768; \
  _Pragma("unroll") for (int i_ = 0; i_ < 4; ++i_) \
    gload_lds16(Ab + (size_t)(i_ * 64 + w * 8 + sr8) * HID + (T) * 64 + scol, \
                la_ + i_ * 8192 + w * 1024); \
  _Pragma("unroll") for (int i_ = 0; i_ < 2; ++i_) \
    gload_lds16(Bb + (size_t)(i_ * 64 + w * 8 + sr8) * HID + (T) * 64 + scol, \
                lb_ + i_ * 8192 + w * 1024); } while (0)

__global__ __launch_bounds__(512, 2) void gemm_f16(
    const f16*  __restrict__ Af,     // (65536, 1024) f16
    const f16*  __restrict__ Wf,     // (1024, 1024) f16
    const float* __restrict__ hvec,  // (32, 1024)
    const float* __restrict__ v,     // (1024)
    float* __restrict__ part)        // (8, MROWS)
{
  extern __shared__ __align__(16) char lds[];   // 147456 B = 3 x (A 32K + B 16K)

  int bid = blockIdx.x;                 // 2048 blocks
  int wg = (bid & 7) * 256 + (bid >> 3);  // bijective XCD-chunked swizzle
  int m_idx = wg >> 3, n_idx = wg & 7;    // n fastest: 8 n-tiles share A panel in L2
  long row0 = (long)m_idx * 256;
  int o0 = n_idx * 128;
  int b = (int)(row0 >> 11);

  int tid = threadIdx.x;
  int l = tid & 63, w = tid >> 6;       // 8 waves
  int wr = w >> 2, wc = w & 3;          // 2 (M) x 4 (N); per-wave 128 x 32 out
  int lr = l & 15, lg = l >> 4;
  int sr8 = l >> 3;                     // staging: 8 lanes per 128-B row
  int scol = ((l & 7) ^ sr8) << 3;      // pre-swizzled global source col (f16)
  int sw = (lr & 7) << 3;               // ds_read-side XOR (row&7 == lr&7)

  const f16* Ab = Af + row0 * HID;
  const f16* Bb = Wf + (size_t)o0 * HID;

  f32x4 acc[8][2];
#pragma unroll
  for (int m = 0; m < 8; ++m) {
    acc[m][0] = (f32x4){0.f, 0.f, 0.f, 0.f};
    acc[m][1] = (f32x4){0.f, 0.f, 0.f, 0.f};
  }

  // prologue: tiles 0 and 1 in flight (12 loads); wait tile 0 (6 remain)
  STG(0); STG(1);
  VMCNT(6); BAR();

  for (int T = 0; T < 16; ++T) {
    if (T + 2 < 16) STG(T + 2);                 // depth-2 prefetch
    const char* la = lds + (T % 3) * 49152;
    const char* lb = la + 32768;

    f16x8 bF[2][2];
#pragma unroll
    for (int n = 0; n < 2; ++n)
#pragma unroll
      for (int ks = 0; ks < 2; ++ks)
        bF[n][ks] = *(const f16x8*)(lb + (wc * 32 + n * 16 + lr) * 128 +
                                    (((ks * 32 + lg * 8) ^ sw) << 1));
    __builtin_amdgcn_s_setprio(1);
#pragma unroll
    for (int m = 0; m < 8; ++m) {
      const char* ra = la + (wr * 128 + m * 16 + lr) * 128;
      f16x8 a0 = *(const f16x8*)(ra + (((lg * 8) ^ sw) << 1));
      f16x8 a1 = *(const f16x8*)(ra + (((32 + lg * 8) ^ sw) << 1));
      acc[m][0] = __builtin_amdgcn_mfma_f32_16x16x32_f16(a0, bF[0][0], acc[m][0], 0, 0, 0);
      acc[m][1] = __builtin_amdgcn_mfma_f32_16x16x32_f16(a0, bF[1][0], acc[m][1], 0, 0, 0);
      acc[m][0] = __builtin_amdgcn_mfma_f32_16x16x32_f16(a1, bF[0][1], acc[m][0], 0, 0, 0);
      acc[m][1] = __builtin_amdgcn_mfma_f32_16x16x32_f16(a1, bF[1][1], acc[m][1], 0, 0, 0);
    }
    __builtin_amdgcn_s_setprio(0);

    if (T < 14)       { VMCNT(6); BAR(); }      // T+1 landed; T+2 still in flight
    else if (T == 14) { VMCNT(0); BAR(); }      // tail: tile 15 complete
  }

  // ---- fused epilogue
  float hvv[2], vvv[2];
#pragma unroll
  for (int n = 0; n < 2; ++n) {
    int o = o0 + wc * 32 + n * 16 + lr;
    hvv[n] = hvec[b * HID + o];
    vvv[n] = v[o];
  }
  float* scf = (float*)lds;
  __syncthreads();
#pragma unroll
  for (int m = 0; m < 8; ++m) {
#pragma unroll
    for (int r = 0; r < 4; ++r) {
      float s = fast_tanh(acc[m][0][r] + hvv[0]) * vvv[0]
              + fast_tanh(acc[m][1][r] + hvv[1]) * vvv[1];
      s += __shfl_xor(s, 1); s += __shfl_xor(s, 2);
      s += __shfl_xor(s, 4); s += __shfl_xor(s, 8);
      if (lr == 0) scf[wc * 256 + wr * 128 + m * 16 + lg * 4 + r] = s;
    }
  }
  __syncthreads();
  if (tid < 256)
    part[(size_t)n_idx * MROWS + row0 + tid] =
        scf[tid] + scf[256 + tid] + scf[512 + tid] + scf[768 + tid];
}

// ---------------------------------------------------------------- kernel 3 (fallback)
// Round-1 kernel verbatim: 128x128 tile, BK=32, on-the-fly f32->f16, part[8][MROWS].
__global__ __launch_bounds__(256, 2) void gemm_fb(
    const float* __restrict__ A, const f16* __restrict__ Wf,
    const float* __restrict__ hvec, const float* __restrict__ v,
    float* __restrict__ part)
{
  __shared__ __align__(16) f16 lA[128][32];
  __shared__ __align__(16) f16 lB[128][32];
  __shared__ float sc[128];

  int bid = blockIdx.x;
  int x = bid & 7, j = bid >> 3;
  int m_idx = x * 64 + (j >> 3);
  int n_idx = j & 7;
  long row0 = (long)m_idx * 128;
  int o0 = n_idx * 128;
  int b = (int)(row0 >> 11);

  int tid = threadIdx.x;
  int l = tid & 63, w = tid >> 6;
  int wr = w >> 1, wc = w & 1;
  int lr = l & 15, lg = l >> 4;

  f32x4 acc[4][4];
#pragma unroll
  for (int m = 0; m < 4; ++m)
#pragma unroll
    for (int n = 0; n < 4; ++n) acc[m][n] = (f32x4){0.f, 0.f, 0.f, 0.f};

  const float* Abase = A + row0 * 1024;

  for (int k0 = 0; k0 < 1024; k0 += 32) {
    __syncthreads();
#pragma unroll
    for (int i = 0; i < 2; ++i) {
      int rr = (i * 256 + tid) >> 2;
      const f16* src = Wf + (size_t)(o0 + rr) * HID + k0 + (tid & 3) * 8;
      char* ldsb = (char*)&lB[0][0] + i * 4096 + w * 1024;
      gload_lds16(src, ldsb);
    }
#pragma unroll
    for (int i = 0; i < 4; ++i) {
      int ja = i * 256 + tid;
      int arow = ja >> 3, ac4 = ja & 7;
      f32x4 d = *(const f32x4*)(Abase + (size_t)arow * 1024 + k0 + ac4 * 4);
      f16x4 q = { (f16)d[0], (f16)d[1], (f16)d[2], (f16)d[3] };
      *(f16x4*)&lA[arow][ac4 * 4] = q;
    }
    __syncthreads();
    f16x8 aF[4], bF[4];
#pragma unroll
    for (int m = 0; m < 4; ++m)
      aF[m] = *(const f16x8*)&lA[wr * 64 + m * 16 + lr][lg * 8];
#pragma unroll
    for (int n = 0; n < 4; ++n)
      bF[n] = *(const f16x8*)&lB[wc * 64 + n * 16 + lr][lg * 8];
#pragma unroll
    for (int m = 0; m < 4; ++m)
#pragma unroll
      for (int n = 0; n < 4; ++n)
        acc[m][n] = __builtin_amdgcn_mfma_f32_16x16x32_f16(aF[m], bF[n], acc[m][n], 0, 0, 0);
  }

  float hv[4], vv[4];
#pragma unroll
  for (int n = 0; n < 4; ++n) {
    int o = o0 + wc * 64 + n * 16 + lr;
    hv[n] = hvec[b * HID + o];
    vv[n] = v[o];
  }
  float myv[4][4];
#pragma unroll
  for (int m = 0; m < 4; ++m) {
#pragma unroll
    for (int r = 0; r < 4; ++r) {
      float s = 0.f;
#pragma unroll
      for (int n = 0; n < 4; ++n)
        s += fast_tanh(acc[m][n][r] + hv[n]) * vv[n];
      s += __shfl_xor(s, 1); s += __shfl_xor(s, 2);
      s += __shfl_xor(s, 4); s += __shfl_xor(s, 8);
      myv[m][r] = s;
    }
  }
  if (wc == 0 && lr == 0) {
#pragma unroll
    for (int m = 0; m < 4; ++m)
#pragma unroll
      for (int r = 0; r < 4; ++r)
        sc[wr * 64 + m * 16 + lg * 4 + r] = myv[m][r];
  }
  __syncthreads();
  if (wc == 1 && lr == 0) {
#pragma unroll
    for (int m = 0; m < 4; ++m)
#pragma unroll
      for (int r = 0; r < 4; ++r)
        sc[wr * 64 + m * 16 + lg * 4 + r] += myv[m][r];
  }
  __syncthreads();
  if (tid < 128)
    part[(size_t)n_idx * MROWS + row0 + tid] = sc[tid];
}

// ---------------------------------------------------------------- kernel 4
__global__ void softmax_k(const float* __restrict__ part, float* __restrict__ out) {
  int b = blockIdx.x;
  __shared__ float srow[SRC];
  __shared__ float red[8];
  int tid = threadIdx.x;  // 256

  float lmax = -1e30f;
  for (int i = tid; i < SRC; i += 256) {
    float s = 0.f;
#pragma unroll
    for (int t = 0; t < 8; ++t)
      s += part[(size_t)t * MROWS + (size_t)b * SRC + i];
    srow[i] = s;
    lmax = fmaxf(lmax, s);
  }
#pragma unroll
  for (int off = 32; off >= 1; off >>= 1)
    lmax = fmaxf(lmax, __shfl_xor(lmax, off));
  if ((tid & 63) == 0) red[tid >> 6] = lmax;
  __syncthreads();
  float bmax = fmaxf(fmaxf(red[0], red[1]), fmaxf(red[2], red[3]));

  float lsum = 0.f;
  for (int i = tid; i < SRC; i += 256) {
    float e = __expf(srow[i] - bmax);
    srow[i] = e;
    lsum += e;
  }
#pragma unroll
  for (int off = 32; off >= 1; off >>= 1)
    lsum += __shfl_xor(lsum, off);
  if ((tid & 63) == 0) red[4 + (tid >> 6)] = lsum;
  __syncthreads();
  float inv = 1.f / (red[4] + red[5] + red[6] + red[7]);
  for (int i = tid; i < SRC; i += 256)
    out[(size_t)b * SRC + i] = srow[i] * inv;
}

// ---------------------------------------------------------------- launch
extern "C" void kernel_launch(void* const* d_in, const int* in_sizes, int n_in,
                              void* d_out, int out_size, void* d_ws, size_t ws_size,
                              hipStream_t stream) {
  const float* hidden = (const float*)d_in[0];
  const float* enc    = (const float*)d_in[1];
  const float* attn_w = (const float*)d_in[2];
  const float* attn_b = (const float*)d_in[3];
  const float* v      = (const float*)d_in[4];
  float* out = (float*)d_out;

  char* ws = (char*)d_ws;
  f16*   Wf   = (f16*)ws;                                 // 2 MB @ 0
  float* hv   = (float*)(ws + (2ull << 20));              // 128 KB
  float* part = (float*)(ws + (2ull << 20) + (128ull << 10)); // 2 MB (8 x 65536 f32)
  f16*   Af   = (f16*)(ws + (8ull << 20));                // 128 MB

  const size_t WS_NEEDED = (8ull << 20) + (128ull << 20) + (1ull << 20);

  convw_k<<<1024, 256, 0, stream>>>(attn_w, Wf);
  hvec_k <<<128,  256, 0, stream>>>(hidden, attn_w, attn_b, hv);

  if (ws_size >= WS_NEEDED) {
    convA_k<<<32768, 256, 0, stream>>>(enc, Af);
    gemm_f16<<<2048, 512, 147456, stream>>>(Af, Wf, hv, v, part);
  } else {
    gemm_fb<<<4096, 256, 0, stream>>>(enc, Wf, hv, v, part);
  }
  softmax_k<<<NBATCH, 256, 0, stream>>>(part, out);
}

// Round 4
// 300.921 us; speedup vs baseline: 1.0620x; 1.0326x over previous
//
#include <hip/hip_runtime.h>
#include <hip/hip_bf16.h>

#define HID    1024
#define NBATCH 32
#define SRC    2048
#define MROWS  (NBATCH * SRC)   // 65536

typedef _Float16 f16;
typedef f16   f16x8 __attribute__((ext_vector_type(8)));
typedef f16   f16x4 __attribute__((ext_vector_type(4)));
typedef float f32x4 __attribute__((ext_vector_type(4)));

#define BAR()    asm volatile("s_barrier" ::: "memory")
#define VMCNT0() asm volatile("s_waitcnt vmcnt(0)" ::: "memory")

__device__ __forceinline__ void gload_lds16(const void* g, void* l) {
  __builtin_amdgcn_global_load_lds(
      (const __attribute__((address_space(1))) void*)g,
      (__attribute__((address_space(3))) void*)l, 16, 0, 0);
}

__device__ __forceinline__ float fast_tanh(float x) {
  x = fminf(fmaxf(x, -15.f), 15.f);
  float e = __expf(2.f * x);
  return (e - 1.f) / (e + 1.f);
}

// ---------------------------------------------------------------- kernel 1
__global__ void convw_k(const float* __restrict__ attn_w, f16* __restrict__ Wf) {
  int idx = blockIdx.x * 256 + threadIdx.x;
  int j = idx * 4;
  int o = j >> 10, h = j & 1023;
  f32x4 d = *(const f32x4*)(attn_w + (size_t)o * 2048 + HID + h);
  f16x4 q = { (f16)d[0], (f16)d[1], (f16)d[2], (f16)d[3] };
  *(f16x4*)(Wf + (size_t)o * HID + h) = q;
}

// ---------------------------------------------------------------- kernel 2
__global__ void hvec_k(const float* __restrict__ hidden,
                       const float* __restrict__ attn_w,
                       const float* __restrict__ attn_b,
                       float* __restrict__ hvec) {
  int idx = blockIdx.x * 256 + threadIdx.x;
  int b = idx >> 10, o = idx & 1023;
  const float* wrow = attn_w + (size_t)o * 2048;
  const float* hrow = hidden + (size_t)b * HID;
  float acc = 0.f;
  for (int h = 0; h < HID; h += 4) {
    f32x4 wv = *(const f32x4*)(wrow + h);
    f32x4 hv = *(const f32x4*)(hrow + h);
    acc += wv[0]*hv[0] + wv[1]*hv[1] + wv[2]*hv[2] + wv[3]*hv[3];
  }
  hvec[idx] = acc + attn_b[o];
}

// ---------------------------------------------------------------- kernel 2b
__global__ void convA_k(const float* __restrict__ A, f16* __restrict__ Af) {
  size_t i = ((size_t)blockIdx.x * 256 + threadIdx.x) * 8;
  f32x4 d0 = *(const f32x4*)(A + i);
  f32x4 d1 = *(const f32x4*)(A + i + 4);
  f16x8 q = { (f16)d0[0], (f16)d0[1], (f16)d0[2], (f16)d0[3],
              (f16)d1[0], (f16)d1[1], (f16)d1[2], (f16)d1[3] };
  *(f16x8*)(Af + i) = q;
}

// ---------------------------------------------------------------- kernel 3
// 256x256 tile, BK=64, 8 waves (2M x 4N, per-wave 128x64), 4 phases/K-tile,
// double-buffered 128 KB LDS, global_load_lds staging (2 issues/phase),
// XOR-swizzle (pre-swizzled global source + swizzled ds_read), setprio MFMA
// clusters, per-tile boundary vmcnt(0) with >=3 phases of latency cover.
// Fused epilogue: part[n_idx][row] = sum_o tanh(C + hvec) * v.

// stage issue q (0..3: A rows q*64.., 4..7: B rows (q-4)*64..) of tile Tn -> buf cd
#define STG1(q, Tn, cd) do { \
  const f16* s_ = ((q) < 4 ? Ab : Bb) + \
      (size_t)(((q) & 3) * 64 + (tid >> 3)) * HID + (Tn) * 64 + scol; \
  char* d_ = lds + (cd) * 65536 + ((q) < 4 ? 0 : 32768) + ((q) & 3) * 8192 + w * 1024; \
  gload_lds16(s_, d_); } while (0)

#define PHASE(P, Tn, c, DOSTG) do { \
  const int mh_ = (P) >> 1, nh_ = (P) & 1; \
  const char* la_ = lds + (c) * 65536; \
  const char* lb_ = la_ + 32768; \
  f16x8 aF[4][2], bF[2][2]; \
  _Pragma("unroll") for (int m4 = 0; m4 < 4; ++m4) { \
    const char* rb = la_ + (wr * 128 + mh_ * 64 + m4 * 16 + lr) * 128; \
    aF[m4][0] = *(const f16x8*)(rb + ((lg ^ sw) << 4)); \
    aF[m4][1] = *(const f16x8*)(rb + (((4 + lg) ^ sw) << 4)); \
  } \
  _Pragma("unroll") for (int n2 = 0; n2 < 2; ++n2) { \
    const char* rb = lb_ + (wc * 64 + nh_ * 32 + n2 * 16 + lr) * 128; \
    bF[n2][0] = *(const f16x8*)(rb + ((lg ^ sw) << 4)); \
    bF[n2][1] = *(const f16x8*)(rb + (((4 + lg) ^ sw) << 4)); \
  } \
  if (DOSTG) { STG1(2 * (P), Tn, (c) ^ 1); STG1(2 * (P) + 1, Tn, (c) ^ 1); } \
  BAR(); \
  asm volatile("s_waitcnt lgkmcnt(0)" ::: "memory"); \
  __builtin_amdgcn_sched_barrier(0); \
  __builtin_amdgcn_s_setprio(1); \
  _Pragma("unroll") for (int ks = 0; ks < 2; ++ks) \
  _Pragma("unroll") for (int m4 = 0; m4 < 4; ++m4) \
  _Pragma("unroll") for (int n2 = 0; n2 < 2; ++n2) \
    acc[mh_ * 4 + m4][nh_ * 2 + n2] = __builtin_amdgcn_mfma_f32_16x16x32_f16( \
        aF[m4][ks], bF[n2][ks], acc[mh_ * 4 + m4][nh_ * 2 + n2], 0, 0, 0); \
  __builtin_amdgcn_s_setprio(0); \
  if ((P) == 3 && (DOSTG)) { VMCNT0(); } \
  BAR(); \
} while (0)

__global__ __launch_bounds__(512, 2) void gemm_f16(
    const f16*  __restrict__ Af,     // (65536, 1024) f16
    const f16*  __restrict__ Wf,     // (1024, 1024) f16
    const float* __restrict__ hvec,  // (32, 1024)
    const float* __restrict__ v,     // (1024)
    float* __restrict__ part)        // (4, MROWS)
{
  extern __shared__ __align__(16) char lds[];   // 131072 = 2 x (A 32K + B 32K)

  int bid = blockIdx.x;                   // 1024 blocks
  int wg = (bid & 7) * 128 + (bid >> 3);  // bijective XCD-chunked swizzle
  int m_idx = wg >> 2, n_idx = wg & 3;    // n fastest: 4 n-tiles share A panel in XCD L2
  long row0 = (long)m_idx * 256;
  int o0 = n_idx * 256;
  int b = (int)(row0 >> 11);

  int tid = threadIdx.x;
  int l = tid & 63, w = tid >> 6;         // 8 waves
  int wr = w >> 2, wc = w & 3;            // 2 (M) x 4 (N)
  int lr = l & 15, lg = l >> 4;
  int sw = lr & 7;                        // ds_read-side 16B-slot XOR
  int scol = ((tid & 7) ^ ((tid >> 3) & 7)) * 8;  // pre-swizzled global col (f16)

  const f16* Ab = Af + row0 * HID;
  const f16* Bb = Wf + (size_t)o0 * HID;

  f32x4 acc[8][4];
#pragma unroll
  for (int m = 0; m < 8; ++m)
#pragma unroll
    for (int n = 0; n < 4; ++n) acc[m][n] = (f32x4){0.f, 0.f, 0.f, 0.f};

  // prologue: stage tile 0 into buf 0
#pragma unroll
  for (int q = 0; q < 8; ++q) { STG1(q, 0, 0); }
  VMCNT0(); BAR();

#pragma unroll 1
  for (int Tp = 0; Tp < 8; ++Tp) {
    const int Ta = Tp * 2, Tb = Ta + 1;
    PHASE(0, Ta + 1, 0, 1); PHASE(1, Ta + 1, 0, 1);
    PHASE(2, Ta + 1, 0, 1); PHASE(3, Ta + 1, 0, 1);
    const int dob = (Tb < 15);
    PHASE(0, Tb + 1, 1, dob); PHASE(1, Tb + 1, 1, dob);
    PHASE(2, Tb + 1, 1, dob); PHASE(3, Tb + 1, 1, dob);
  }

  // ---- fused epilogue: tanh(C + hvec) . v reduced over this block's 256 o's
  float hvv[4], vvv[4];
#pragma unroll
  for (int n = 0; n < 4; ++n) {
    int o = o0 + wc * 64 + n * 16 + lr;
    hvv[n] = hvec[b * HID + o];
    vvv[n] = v[o];
  }
  float* scf = (float*)lds;
  __syncthreads();
#pragma unroll
  for (int m = 0; m < 8; ++m) {
#pragma unroll
    for (int r = 0; r < 4; ++r) {
      float s = 0.f;
#pragma unroll
      for (int n = 0; n < 4; ++n)
        s += fast_tanh(acc[m][n][r] + hvv[n]) * vvv[n];
      s += __shfl_xor(s, 1); s += __shfl_xor(s, 2);
      s += __shfl_xor(s, 4); s += __shfl_xor(s, 8);
      if (lr == 0) scf[wc * 256 + wr * 128 + m * 16 + lg * 4 + r] = s;
    }
  }
  __syncthreads();
  if (tid < 256)
    part[(size_t)n_idx * MROWS + row0 + tid] =
        scf[tid] + scf[256 + tid] + scf[512 + tid] + scf[768 + tid];
}

// ---------------------------------------------------------------- kernel 3 (fallback)
__global__ __launch_bounds__(256, 2) void gemm_fb(
    const float* __restrict__ A, const f16* __restrict__ Wf,
    const float* __restrict__ hvec, const float* __restrict__ v,
    float* __restrict__ part)
{
  __shared__ __align__(16) f16 lA[128][32];
  __shared__ __align__(16) f16 lB[128][32];
  __shared__ float sc[128];

  int bid = blockIdx.x;
  int x = bid & 7, j = bid >> 3;
  int m_idx = x * 64 + (j >> 3);
  int n_idx = j & 7;
  long row0 = (long)m_idx * 128;
  int o0 = n_idx * 128;
  int b = (int)(row0 >> 11);

  int tid = threadIdx.x;
  int l = tid & 63, w = tid >> 6;
  int wr = w >> 1, wc = w & 1;
  int lr = l & 15, lg = l >> 4;

  f32x4 acc[4][4];
#pragma unroll
  for (int m = 0; m < 4; ++m)
#pragma unroll
    for (int n = 0; n < 4; ++n) acc[m][n] = (f32x4){0.f, 0.f, 0.f, 0.f};

  const float* Abase = A + row0 * 1024;

  for (int k0 = 0; k0 < 1024; k0 += 32) {
    __syncthreads();
#pragma unroll
    for (int i = 0; i < 2; ++i) {
      int rr = (i * 256 + tid) >> 2;
      const f16* src = Wf + (size_t)(o0 + rr) * HID + k0 + (tid & 3) * 8;
      char* ldsb = (char*)&lB[0][0] + i * 4096 + w * 1024;
      gload_lds16(src, ldsb);
    }
#pragma unroll
    for (int i = 0; i < 4; ++i) {
      int ja = i * 256 + tid;
      int arow = ja >> 3, ac4 = ja & 7;
      f32x4 d = *(const f32x4*)(Abase + (size_t)arow * 1024 + k0 + ac4 * 4);
      f16x4 q = { (f16)d[0], (f16)d[1], (f16)d[2], (f16)d[3] };
      *(f16x4*)&lA[arow][ac4 * 4] = q;
    }
    __syncthreads();
    f16x8 aF[4], bF[4];
#pragma unroll
    for (int m = 0; m < 4; ++m)
      aF[m] = *(const f16x8*)&lA[wr * 64 + m * 16 + lr][lg * 8];
#pragma unroll
    for (int n = 0; n < 4; ++n)
      bF[n] = *(const f16x8*)&lB[wc * 64 + n * 16 + lr][lg * 8];
#pragma unroll
    for (int m = 0; m < 4; ++m)
#pragma unroll
      for (int n = 0; n < 4; ++n)
        acc[m][n] = __builtin_amdgcn_mfma_f32_16x16x32_f16(aF[m], bF[n], acc[m][n], 0, 0, 0);
  }

  float hv[4], vv[4];
#pragma unroll
  for (int n = 0; n < 4; ++n) {
    int o = o0 + wc * 64 + n * 16 + lr;
    hv[n] = hvec[b * HID + o];
    vv[n] = v[o];
  }
  float myv[4][4];
#pragma unroll
  for (int m = 0; m < 4; ++m) {
#pragma unroll
    for (int r = 0; r < 4; ++r) {
      float s = 0.f;
#pragma unroll
      for (int n = 0; n < 4; ++n)
        s += fast_tanh(acc[m][n][r] + hv[n]) * vv[n];
      s += __shfl_xor(s, 1); s += __shfl_xor(s, 2);
      s += __shfl_xor(s, 4); s += __shfl_xor(s, 8);
      myv[m][r] = s;
    }
  }
  if (wc == 0 && lr == 0) {
#pragma unroll
    for (int m = 0; m < 4; ++m)
#pragma unroll
      for (int r = 0; r < 4; ++r)
        sc[wr * 64 + m * 16 + lg * 4 + r] = myv[m][r];
  }
  __syncthreads();
  if (wc == 1 && lr == 0) {
#pragma unroll
    for (int m = 0; m < 4; ++m)
#pragma unroll
      for (int r = 0; r < 4; ++r)
        sc[wr * 64 + m * 16 + lg * 4 + r] += myv[m][r];
  }
  __syncthreads();
  if (tid < 128)
    part[(size_t)n_idx * MROWS + row0 + tid] = sc[tid];
}

// ---------------------------------------------------------------- kernel 4
__global__ void softmax_k(const float* __restrict__ part, float* __restrict__ out,
                          int nsl) {
  int b = blockIdx.x;
  __shared__ float srow[SRC];
  __shared__ float red[8];
  int tid = threadIdx.x;  // 256

  float lmax = -1e30f;
  for (int i = tid; i < SRC; i += 256) {
    float s = 0.f;
    for (int t = 0; t < nsl; ++t)
      s += part[(size_t)t * MROWS + (size_t)b * SRC + i];
    srow[i] = s;
    lmax = fmaxf(lmax, s);
  }
#pragma unroll
  for (int off = 32; off >= 1; off >>= 1)
    lmax = fmaxf(lmax, __shfl_xor(lmax, off));
  if ((tid & 63) == 0) red[tid >> 6] = lmax;
  __syncthreads();
  float bmax = fmaxf(fmaxf(red[0], red[1]), fmaxf(red[2], red[3]));

  float lsum = 0.f;
  for (int i = tid; i < SRC; i += 256) {
    float e = __expf(srow[i] - bmax);
    srow[i] = e;
    lsum += e;
  }
#pragma unroll
  for (int off = 32; off >= 1; off >>= 1)
    lsum += __shfl_xor(lsum, off);
  if ((tid & 63) == 0) red[4 + (tid >> 6)] = lsum;
  __syncthreads();
  float inv = 1.f / (red[4] + red[5] + red[6] + red[7]);
  for (int i = tid; i < SRC; i += 256)
    out[(size_t)b * SRC + i] = srow[i] * inv;
}

// ---------------------------------------------------------------- launch
extern "C" void kernel_launch(void* const* d_in, const int* in_sizes, int n_in,
                              void* d_out, int out_size, void* d_ws, size_t ws_size,
                              hipStream_t stream) {
  const float* hidden = (const float*)d_in[0];
  const float* enc    = (const float*)d_in[1];
  const float* attn_w = (const float*)d_in[2];
  const float* attn_b = (const float*)d_in[3];
  const float* v      = (const float*)d_in[4];
  float* out = (float*)d_out;

  char* ws = (char*)d_ws;
  f16*   Wf   = (f16*)ws;                                     // 2 MB @ 0
  float* hv   = (float*)(ws + (2ull << 20));                  // 128 KB
  float* part = (float*)(ws + (2ull << 20) + (128ull << 10)); // 2 MB (8 x 65536 f32 max)
  f16*   Af   = (f16*)(ws + (8ull << 20));                    // 128 MB

  const size_t WS_NEEDED = (8ull << 20) + (128ull << 20);

  convw_k<<<1024, 256, 0, stream>>>(attn_w, Wf);
  hvec_k <<<128,  256, 0, stream>>>(hidden, attn_w, attn_b, hv);

  if (ws_size >= WS_NEEDED) {
    convA_k<<<32768, 256, 0, stream>>>(enc, Af);
    gemm_f16<<<1024, 512, 131072, stream>>>(Af, Wf, hv, v, part);
    softmax_k<<<NBATCH, 256, 0, stream>>>(part, out, 4);
  } else {
    gemm_fb<<<4096, 256, 0, stream>>>(enc, Wf, hv, v, part);
    softmax_k<<<NBATCH, 256, 0, stream>>>(part, out, 8);
  }
}

// Round 5
// 291.718 us; speedup vs baseline: 1.0955x; 1.0315x over previous
//
#include <hip/hip_runtime.h>
#include <hip/hip_bf16.h>

#define HID    1024
#define NBATCH 32
#define SRC    2048
#define MROWS  (NBATCH * SRC)   // 65536

typedef _Float16 f16;
typedef f16   f16x8 __attribute__((ext_vector_type(8)));
typedef f16   f16x4 __attribute__((ext_vector_type(4)));
typedef float f32x4 __attribute__((ext_vector_type(4)));

#define BAR()    __builtin_amdgcn_s_barrier()
#define LGKM0()  asm volatile("s_waitcnt lgkmcnt(0)")
#define VMCNT0() asm volatile("s_waitcnt vmcnt(0)")
#define SCHED0() __builtin_amdgcn_sched_barrier(0)

__device__ __forceinline__ void gload_lds16(const void* g, void* l) {
  __builtin_amdgcn_global_load_lds(
      (const __attribute__((address_space(1))) void*)g,
      (__attribute__((address_space(3))) void*)l, 16, 0, 0);
}

__device__ __forceinline__ float fast_tanh(float x) {
  x = fminf(fmaxf(x, -15.f), 15.f);
  float e = __expf(2.f * x);
  return (e - 1.f) / (e + 1.f);
}

// ---------------------------------------------------------------- kernel 1
__global__ void convw_k(const float* __restrict__ attn_w, f16* __restrict__ Wf) {
  int idx = blockIdx.x * 256 + threadIdx.x;
  int j = idx * 4;
  int o = j >> 10, h = j & 1023;
  f32x4 d = *(const f32x4*)(attn_w + (size_t)o * 2048 + HID + h);
  f16x4 q = { (f16)d[0], (f16)d[1], (f16)d[2], (f16)d[3] };
  *(f16x4*)(Wf + (size_t)o * HID + h) = q;
}

// ---------------------------------------------------------------- kernel 2
__global__ void hvec_k(const float* __restrict__ hidden,
                       const float* __restrict__ attn_w,
                       const float* __restrict__ attn_b,
                       float* __restrict__ hvec) {
  int idx = blockIdx.x * 256 + threadIdx.x;
  int b = idx >> 10, o = idx & 1023;
  const float* wrow = attn_w + (size_t)o * 2048;
  const float* hrow = hidden + (size_t)b * HID;
  float acc = 0.f;
  for (int h = 0; h < HID; h += 4) {
    f32x4 wv = *(const f32x4*)(wrow + h);
    f32x4 hv = *(const f32x4*)(hrow + h);
    acc += wv[0]*hv[0] + wv[1]*hv[1] + wv[2]*hv[2] + wv[3]*hv[3];
  }
  hvec[idx] = acc + attn_b[o];
}

// ---------------------------------------------------------------- kernel 2b
__global__ void convA_k(const float* __restrict__ A, f16* __restrict__ Af) {
  size_t i = ((size_t)blockIdx.x * 256 + threadIdx.x) * 8;
  f32x4 d0 = *(const f32x4*)(A + i);
  f32x4 d1 = *(const f32x4*)(A + i + 4);
  f16x8 q = { (f16)d0[0], (f16)d0[1], (f16)d0[2], (f16)d0[3],
              (f16)d1[0], (f16)d1[1], (f16)d1[2], (f16)d1[3] };
  *(f16x8*)(Af + i) = q;
}

// ---------------------------------------------------------------- kernel 3
// 256x256 tile, BK=64, 8 waves (2M x 4N, per-wave 128x64), double-buffered
// 128 KB LDS, global_load_lds staging. ZIGZAG phases per K-tile:
//   P0 (mh0,nh0): read aF(mh0)+bF0(nh0)  [12 b128]  + stage A of T+1
//   P1 (mh0,nh1): read bF1(nh1)          [ 4 b128]  + stage B of T+1
//   P2 (mh1,nh1): read aF(mh1)           [ 8 b128]
//   P3 (mh1,nh0): no reads (aF,bF0 held in regs); vmcnt(0) w/ ~3 phases cover
// => every fragment read from LDS exactly once per K-tile (24 KB/wave).

#define STG_A(Tn, cd) do { \
  _Pragma("unroll") for (int q_ = 0; q_ < 4; ++q_) \
    gload_lds16(Ab + (size_t)(q_ * 64 + (tid >> 3)) * HID + (Tn) * 64 + scol, \
                lds + (cd) * 65536 + q_ * 8192 + w * 1024); } while (0)
#define STG_B(Tn, cd) do { \
  _Pragma("unroll") for (int q_ = 0; q_ < 4; ++q_) \
    gload_lds16(Bb + (size_t)(q_ * 64 + (tid >> 3)) * HID + (Tn) * 64 + scol, \
                lds + (cd) * 65536 + 32768 + q_ * 8192 + w * 1024); } while (0)

#define RD_A(la_, mh_) do { \
  _Pragma("unroll") for (int m4 = 0; m4 < 4; ++m4) { \
    const char* rb = (la_) + (wr * 128 + (mh_) * 64 + m4 * 16 + lr) * 128; \
    aF[m4][0] = *(const f16x8*)(rb + ((lg ^ sw) << 4)); \
    aF[m4][1] = *(const f16x8*)(rb + (((4 + lg) ^ sw) << 4)); } } while (0)
#define RD_B(lb_, dst, nh_) do { \
  _Pragma("unroll") for (int n2 = 0; n2 < 2; ++n2) { \
    const char* rb = (lb_) + (wc * 64 + (nh_) * 32 + n2 * 16 + lr) * 128; \
    dst[n2][0] = *(const f16x8*)(rb + ((lg ^ sw) << 4)); \
    dst[n2][1] = *(const f16x8*)(rb + (((4 + lg) ^ sw) << 4)); } } while (0)

#define MFMA16(bsrc, mo, no) do { \
  __builtin_amdgcn_s_setprio(1); \
  _Pragma("unroll") for (int ks = 0; ks < 2; ++ks) \
  _Pragma("unroll") for (int m4 = 0; m4 < 4; ++m4) \
  _Pragma("unroll") for (int n2 = 0; n2 < 2; ++n2) \
    acc[(mo) + m4][(no) + n2] = __builtin_amdgcn_mfma_f32_16x16x32_f16( \
        aF[m4][ks], bsrc[n2][ks], acc[(mo) + m4][(no) + n2], 0, 0, 0); \
  __builtin_amdgcn_s_setprio(0); } while (0)

#define TILE(c, Tn, DOSTG) do { \
  const char* la_ = lds + (c) * 65536; \
  const char* lb_ = la_ + 32768; \
  /* P0 */ \
  RD_A(la_, 0); RD_B(lb_, bF0, 0); \
  if (DOSTG) STG_A(Tn, (c) ^ 1); \
  BAR(); LGKM0(); SCHED0(); \
  MFMA16(bF0, 0, 0); \
  BAR(); SCHED0(); \
  /* P1 */ \
  RD_B(lb_, bF1, 1); \
  if (DOSTG) STG_B(Tn, (c) ^ 1); \
  BAR(); LGKM0(); SCHED0(); \
  MFMA16(bF1, 0, 2); \
  BAR(); SCHED0(); \
  /* P2 */ \
  RD_A(la_, 1); \
  BAR(); LGKM0(); SCHED0(); \
  MFMA16(bF1, 4, 2); \
  BAR(); SCHED0(); \
  /* P3 */ \
  MFMA16(bF0, 4, 0); \
  if (DOSTG) { VMCNT0(); SCHED0(); } \
  BAR(); SCHED0(); \
} while (0)

__global__ __launch_bounds__(512, 2) void gemm_f16(
    const f16*  __restrict__ Af,     // (65536, 1024) f16
    const f16*  __restrict__ Wf,     // (1024, 1024) f16
    const float* __restrict__ hvec,  // (32, 1024)
    const float* __restrict__ v,     // (1024)
    float* __restrict__ part)        // (4, MROWS)
{
  extern __shared__ __align__(16) char lds[];   // 131072 = 2 x (A 32K + B 32K)

  int bid = blockIdx.x;                   // 1024 blocks
  int wg = (bid & 7) * 128 + (bid >> 3);  // bijective XCD-chunked swizzle
  int m_idx = wg >> 2, n_idx = wg & 3;    // n fastest: 4 n-tiles share A panel in XCD L2
  long row0 = (long)m_idx * 256;
  int o0 = n_idx * 256;
  int b = (int)(row0 >> 11);

  int tid = threadIdx.x;
  int l = tid & 63, w = tid >> 6;         // 8 waves
  int wr = w >> 2, wc = w & 3;            // 2 (M) x 4 (N)
  int lr = l & 15, lg = l >> 4;
  int sw = lr & 7;                        // ds_read-side 16B-slot XOR
  int scol = ((tid & 7) ^ ((tid >> 3) & 7)) * 8;  // pre-swizzled global col (f16)

  const f16* Ab = Af + row0 * HID;
  const f16* Bb = Wf + (size_t)o0 * HID;

  f32x4 acc[8][4];
#pragma unroll
  for (int m = 0; m < 8; ++m)
#pragma unroll
    for (int n = 0; n < 4; ++n) acc[m][n] = (f32x4){0.f, 0.f, 0.f, 0.f};

  f16x8 aF[4][2], bF0[2][2], bF1[2][2];

  // prologue: stage tile 0 into buf 0
  STG_A(0, 0); STG_B(0, 0);
  VMCNT0(); SCHED0(); BAR(); SCHED0();

#pragma unroll 1
  for (int Tp = 0; Tp < 8; ++Tp) {
    const int Ta = Tp * 2, Tb = Ta + 1;
    TILE(0, Ta + 1, 1);
    TILE(1, Tb + 1, (Tb < 15));
  }

  // ---- fused epilogue: tanh(C + hvec) . v reduced over this block's 256 o's
  float hvv[4], vvv[4];
#pragma unroll
  for (int n = 0; n < 4; ++n) {
    int o = o0 + wc * 64 + n * 16 + lr;
    hvv[n] = hvec[b * HID + o];
    vvv[n] = v[o];
  }
  float* scf = (float*)lds;
  __syncthreads();
#pragma unroll
  for (int m = 0; m < 8; ++m) {
#pragma unroll
    for (int r = 0; r < 4; ++r) {
      float s = 0.f;
#pragma unroll
      for (int n = 0; n < 4; ++n)
        s += fast_tanh(acc[m][n][r] + hvv[n]) * vvv[n];
      s += __shfl_xor(s, 1); s += __shfl_xor(s, 2);
      s += __shfl_xor(s, 4); s += __shfl_xor(s, 8);
      if (lr == 0) scf[wc * 256 + wr * 128 + m * 16 + lg * 4 + r] = s;
    }
  }
  __syncthreads();
  if (tid < 256)
    part[(size_t)n_idx * MROWS + row0 + tid] =
        scf[tid] + scf[256 + tid] + scf[512 + tid] + scf[768 + tid];
}

// ---------------------------------------------------------------- kernel 3 (fallback)
__global__ __launch_bounds__(256, 2) void gemm_fb(
    const float* __restrict__ A, const f16* __restrict__ Wf,
    const float* __restrict__ hvec, const float* __restrict__ v,
    float* __restrict__ part)
{
  __shared__ __align__(16) f16 lA[128][32];
  __shared__ __align__(16) f16 lB[128][32];
  __shared__ float sc[128];

  int bid = blockIdx.x;
  int x = bid & 7, j = bid >> 3;
  int m_idx = x * 64 + (j >> 3);
  int n_idx = j & 7;
  long row0 = (long)m_idx * 128;
  int o0 = n_idx * 128;
  int b = (int)(row0 >> 11);

  int tid = threadIdx.x;
  int l = tid & 63, w = tid >> 6;
  int wr = w >> 1, wc = w & 1;
  int lr = l & 15, lg = l >> 4;

  f32x4 acc[4][4];
#pragma unroll
  for (int m = 0; m < 4; ++m)
#pragma unroll
    for (int n = 0; n < 4; ++n) acc[m][n] = (f32x4){0.f, 0.f, 0.f, 0.f};

  const float* Abase = A + row0 * 1024;

  for (int k0 = 0; k0 < 1024; k0 += 32) {
    __syncthreads();
#pragma unroll
    for (int i = 0; i < 2; ++i) {
      int rr = (i * 256 + tid) >> 2;
      const f16* src = Wf + (size_t)(o0 + rr) * HID + k0 + (tid & 3) * 8;
      char* ldsb = (char*)&lB[0][0] + i * 4096 + w * 1024;
      gload_lds16(src, ldsb);
    }
#pragma unroll
    for (int i = 0; i < 4; ++i) {
      int ja = i * 256 + tid;
      int arow = ja >> 3, ac4 = ja & 7;
      f32x4 d = *(const f32x4*)(Abase + (size_t)arow * 1024 + k0 + ac4 * 4);
      f16x4 q = { (f16)d[0], (f16)d[1], (f16)d[2], (f16)d[3] };
      *(f16x4*)&lA[arow][ac4 * 4] = q;
    }
    __syncthreads();
    f16x8 aF[4], bF[4];
#pragma unroll
    for (int m = 0; m < 4; ++m)
      aF[m] = *(const f16x8*)&lA[wr * 64 + m * 16 + lr][lg * 8];
#pragma unroll
    for (int n = 0; n < 4; ++n)
      bF[n] = *(const f16x8*)&lB[wc * 64 + n * 16 + lr][lg * 8];
#pragma unroll
    for (int m = 0; m < 4; ++m)
#pragma unroll
      for (int n = 0; n < 4; ++n)
        acc[m][n] = __builtin_amdgcn_mfma_f32_16x16x32_f16(aF[m], bF[n], acc[m][n], 0, 0, 0);
  }

  float hv[4], vv[4];
#pragma unroll
  for (int n = 0; n < 4; ++n) {
    int o = o0 + wc * 64 + n * 16 + lr;
    hv[n] = hvec[b * HID + o];
    vv[n] = v[o];
  }
  float myv[4][4];
#pragma unroll
  for (int m = 0; m < 4; ++m) {
#pragma unroll
    for (int r = 0; r < 4; ++r) {
      float s = 0.f;
#pragma unroll
      for (int n = 0; n < 4; ++n)
        s += fast_tanh(acc[m][n][r] + hv[n]) * vv[n];
      s += __shfl_xor(s, 1); s += __shfl_xor(s, 2);
      s += __shfl_xor(s, 4); s += __shfl_xor(s, 8);
      myv[m][r] = s;
    }
  }
  if (wc == 0 && lr == 0) {
#pragma unroll
    for (int m = 0; m < 4; ++m)
#pragma unroll
      for (int r = 0; r < 4; ++r)
        sc[wr * 64 + m * 16 + lg * 4 + r] = myv[m][r];
  }
  __syncthreads();
  if (wc == 1 && lr == 0) {
#pragma unroll
    for (int m = 0; m < 4; ++m)
#pragma unroll
      for (int r = 0; r < 4; ++r)
        sc[wr * 64 + m * 16 + lg * 4 + r] += myv[m][r];
  }
  __syncthreads();
  if (tid < 128)
    part[(size_t)n_idx * MROWS + row0 + tid] = sc[tid];
}

// ---------------------------------------------------------------- kernel 4
__global__ void softmax_k(const float* __restrict__ part, float* __restrict__ out,
                          int nsl) {
  int b = blockIdx.x;
  __shared__ float srow[SRC];
  __shared__ float red[8];
  int tid = threadIdx.x;  // 256

  float lmax = -1e30f;
  for (int i = tid; i < SRC; i += 256) {
    float s = 0.f;
    for (int t = 0; t < nsl; ++t)
      s += part[(size_t)t * MROWS + (size_t)b * SRC + i];
    srow[i] = s;
    lmax = fmaxf(lmax, s);
  }
#pragma unroll
  for (int off = 32; off >= 1; off >>= 1)
    lmax = fmaxf(lmax, __shfl_xor(lmax, off));
  if ((tid & 63) == 0) red[tid >> 6] = lmax;
  __syncthreads();
  float bmax = fmaxf(fmaxf(red[0], red[1]), fmaxf(red[2], red[3]));

  float lsum = 0.f;
  for (int i = tid; i < SRC; i += 256) {
    float e = __expf(srow[i] - bmax);
    srow[i] = e;
    lsum += e;
  }
#pragma unroll
  for (int off = 32; off >= 1; off >>= 1)
    lsum += __shfl_xor(lsum, off);
  if ((tid & 63) == 0) red[4 + (tid >> 6)] = lsum;
  __syncthreads();
  float inv = 1.f / (red[4] + red[5] + red[6] + red[7]);
  for (int i = tid; i < SRC; i += 256)
    out[(size_t)b * SRC + i] = srow[i] * inv;
}

// ---------------------------------------------------------------- launch
extern "C" void kernel_launch(void* const* d_in, const int* in_sizes, int n_in,
                              void* d_out, int out_size, void* d_ws, size_t ws_size,
                              hipStream_t stream) {
  const float* hidden = (const float*)d_in[0];
  const float* enc    = (const float*)d_in[1];
  const float* attn_w = (const float*)d_in[2];
  const float* attn_b = (const float*)d_in[3];
  const float* v      = (const float*)d_in[4];
  float* out = (float*)d_out;

  char* ws = (char*)d_ws;
  f16*   Wf   = (f16*)ws;                                     // 2 MB @ 0
  float* hv   = (float*)(ws + (2ull << 20));                  // 128 KB
  float* part = (float*)(ws + (2ull << 20) + (128ull << 10)); // 2 MB max
  f16*   Af   = (f16*)(ws + (8ull << 20));                    // 128 MB

  const size_t WS_NEEDED = (8ull << 20) + (128ull << 20);

  convw_k<<<1024, 256, 0, stream>>>(attn_w, Wf);
  hvec_k <<<128,  256, 0, stream>>>(hidden, attn_w, attn_b, hv);

  if (ws_size >= WS_NEEDED) {
    convA_k<<<32768, 256, 0, stream>>>(enc, Af);
    gemm_f16<<<1024, 512, 131072, stream>>>(Af, Wf, hv, v, part);
    softmax_k<<<NBATCH, 256, 0, stream>>>(part, out, 4);
  } else {
    gemm_fb<<<4096, 256, 0, stream>>>(enc, Wf, hv, v, part);
    softmax_k<<<NBATCH, 256, 0, stream>>>(part, out, 8);
  }
}